// Round 1
// baseline (426.888 us; speedup 1.0000x reference)
//
#include <hip/hip_runtime.h>
#include <math.h>

// SCALE computed in double then rounded, to match Python's float64 constant folding.
static constexpr float SCALE_F = (float)(2.0 * 28.0 * 0.32178);

// order-preserving float<->uint bijection for atomic max on floats
__device__ __forceinline__ unsigned mapf(float f){
    unsigned u = __float_as_uint(f);
    return (u & 0x80000000u) ? ~u : (u | 0x80000000u);
}
__device__ __forceinline__ float unmapf(unsigned m){
    unsigned u = (m & 0x80000000u) ? (m ^ 0x80000000u) : ~m;
    return __uint_as_float(u);
}
__device__ __forceinline__ float eluf(float x){
    return x > 0.f ? x : expm1f(x);
}

__global__ void init_max_kernel(unsigned* __restrict__ p, int n){
    int i = blockIdx.x*blockDim.x + threadIdx.x;
    int stride = gridDim.x*blockDim.x;
    for(; i < n; i += stride) p[i] = 0x007FFFFFu; // mapf(-inf)
}

// rows is sorted ascending; rp[n] = lower_bound(rows, n), for n in [0, Nn]
__global__ void build_rowptr(const int* __restrict__ rows, int E, int Nn, int* __restrict__ rp){
    int n = blockIdx.x*blockDim.x + threadIdx.x;
    if (n > Nn) return;
    int lo = 0, hi = E;
    while (lo < hi){ int mid = (lo+hi) >> 1; if (rows[mid] < n) lo = mid+1; else hi = mid; }
    rp[n] = lo;
}

// Layer 1: I=1, O=32. One thread per node. Gather formulation (symmetric edge list).
__global__ void l1_kernel(const float* __restrict__ x, const float* __restrict__ pos,
                          const int* __restrict__ ei1, int E1,
                          const int* __restrict__ rp1, const int* __restrict__ cl1,
                          const float* __restrict__ g1, const float* __restrict__ mu1,
                          const float* __restrict__ sg1, const float* __restrict__ rt1,
                          const float* __restrict__ b1,
                          unsigned* __restrict__ h2m, float* __restrict__ pos2s,
                          float* __restrict__ cntc1, int N)
{
    int n = blockIdx.x*blockDim.x + threadIdx.x;
    if (n >= N) return;
    const int* cols = ei1 + E1;
    float mx[9], my[9], ivx[9], ivy[9];
    #pragma unroll
    for (int k = 0; k < 9; k++){
        mx[k] = mu1[2*k]; my[k] = mu1[2*k+1];
        float sx = sg1[2*k], sy = sg1[2*k+1];
        ivx[k] = 1.f/(sx*sx); ivy[k] = 1.f/(sy*sy);
    }
    float px = pos[2*n], py = pos[2*n+1];
    float s[9];
    #pragma unroll
    for (int k = 0; k < 9; k++) s[k] = 0.f;
    int e0 = rp1[n], e1 = rp1[n+1];
    for (int e = e0; e < e1; e++){
        int j = cols[e];
        // original contributing edge is (j -> n): pseudo = (pos[n]-pos[j])/SCALE + 0.5
        float ux = (px - pos[2*j])/SCALE_F + 0.5f;
        float uy = (py - pos[2*j+1])/SCALE_F + 0.5f;
        float xj = x[j];
        #pragma unroll
        for (int k = 0; k < 9; k++){
            float dx = ux - mx[k], dy = uy - my[k];
            s[k] += xj * expf(-0.5f*(dx*dx*ivx[k] + dy*dy*ivy[k]));
        }
    }
    float inv = 1.f / (float)max(e1 - e0, 1);
    int c = cl1[n];
    float xn = x[n];
    for (int o = 0; o < 32; o++){
        float acc = 0.f;
        #pragma unroll
        for (int k = 0; k < 9; k++) acc += g1[k*32+o] * s[k];
        float v = acc*inv + xn*rt1[o] + b1[o];
        atomicMax(&h2m[(size_t)c*32 + o], mapf(eluf(v)));
    }
    atomicAdd(&pos2s[2*c],   px);
    atomicAdd(&pos2s[2*c+1], py);
    atomicAdd(&cntc1[c], 1.f);
}

__global__ void posdiv_kernel(float* __restrict__ ps, const float* __restrict__ cnt, int C){
    int c = blockIdx.x*blockDim.x + threadIdx.x;
    if (c >= C) return;
    float cm = fmaxf(cnt[c], 1.f);
    ps[2*c]   = ps[2*c]   / cm;
    ps[2*c+1] = ps[2*c+1] / cm;
}

// Layer 2: I=32, O=64. One 64-thread block per node.
// S[i,k] = sum_j x[j,i]*w_k(j) in LDS, then out[o] = sum_{i,k} g[i,k,o]*S[i,k].
__global__ __launch_bounds__(64) void l2_kernel(const unsigned* __restrict__ h2m,
    const float* __restrict__ pos2,
    const int* __restrict__ ei2, int E2, const int* __restrict__ rp2, const int* __restrict__ cl2,
    const float* __restrict__ g2, const float* __restrict__ mu2, const float* __restrict__ sg2,
    const float* __restrict__ rt2, const float* __restrict__ b2,
    unsigned* __restrict__ h3m, float* __restrict__ pos3s, float* __restrict__ cntc2)
{
    int n = blockIdx.x;
    int t = threadIdx.x;
    __shared__ float S[288];        // [i=32][k=9]
    __shared__ float Wc[64*9];      // per-chunk edge weights
    __shared__ float xn_s[32];
    __shared__ float mus[18], ivs[18];
    if (t < 9){
        mus[2*t] = mu2[2*t]; mus[2*t+1] = mu2[2*t+1];
        float sx = sg2[2*t], sy = sg2[2*t+1];
        ivs[2*t] = 1.f/(sx*sx); ivs[2*t+1] = 1.f/(sy*sy);
    }
    if (t < 32) xn_s[t] = unmapf(h2m[(size_t)n*32 + t]);
    int e0 = rp2[n], e1 = rp2[n+1];
    int deg = e1 - e0;
    float px = pos2[2*n], py = pos2[2*n+1];
    const int* cols = ei2 + E2;
    int i  = t & 31;
    int kg = t >> 5;           // 0: k=0..4, 1: k=5..8
    int k0 = kg * 5;
    int nk = kg ? 4 : 5;
    float sacc[5] = {0.f,0.f,0.f,0.f,0.f};
    __syncthreads();
    for (int base = e0; base < e1; base += 64){
        int ne = min(64, e1 - base);
        if (t < ne){
            int j = cols[base + t];
            float ux = (px - pos2[2*j])/SCALE_F + 0.5f;
            float uy = (py - pos2[2*j+1])/SCALE_F + 0.5f;
            #pragma unroll
            for (int k = 0; k < 9; k++){
                float dx = ux - mus[2*k], dy = uy - mus[2*k+1];
                Wc[t*9+k] = expf(-0.5f*(dx*dx*ivs[2*k] + dy*dy*ivs[2*k+1]));
            }
        }
        __syncthreads();
        for (int jj = 0; jj < ne; jj++){
            int j = cols[base + jj];
            float xji = unmapf(h2m[(size_t)j*32 + i]);
            #pragma unroll
            for (int kk = 0; kk < 5; kk++){
                if (kk < nk) sacc[kk] += xji * Wc[jj*9 + k0 + kk];
            }
        }
        __syncthreads();
    }
    #pragma unroll
    for (int kk = 0; kk < 5; kk++) if (kk < nk) S[i*9 + k0 + kk] = sacc[kk];
    __syncthreads();
    float inv = 1.f / (float)max(deg, 1);
    float acc = 0.f;
    #pragma unroll 4
    for (int idx = 0; idx < 288; idx++) acc += g2[idx*64 + t] * S[idx];
    float r = 0.f;
    #pragma unroll 4
    for (int ii = 0; ii < 32; ii++) r += xn_s[ii] * rt2[ii*64 + t];
    float h = eluf(acc*inv + r + b2[t]);
    int c = cl2[n];
    atomicMax(&h3m[(size_t)c*64 + t], mapf(h));
    if (t == 0){
        atomicAdd(&pos3s[2*c],   px);
        atomicAdd(&pos3s[2*c+1], py);
        atomicAdd(&cntc2[c], 1.f);
    }
}

// Layer 3: I=64, O=64. One 64-thread block per node. Output accumulated into gsum (graph mean numerator).
__global__ __launch_bounds__(64) void l3_kernel(const unsigned* __restrict__ h3m,
    const float* __restrict__ pos3,
    const int* __restrict__ ei3, int E3, const int* __restrict__ rp3,
    const float* __restrict__ g3, const float* __restrict__ mu3, const float* __restrict__ sg3,
    const float* __restrict__ rt3, const float* __restrict__ b3,
    float* __restrict__ gsum)
{
    int n = blockIdx.x, t = threadIdx.x;
    __shared__ float S[576];        // [i=64][k=9]
    __shared__ float Wc[64*9];
    __shared__ float xn_s[64];
    __shared__ float mus[18], ivs[18];
    if (t < 9){
        mus[2*t] = mu3[2*t]; mus[2*t+1] = mu3[2*t+1];
        float sx = sg3[2*t], sy = sg3[2*t+1];
        ivs[2*t] = 1.f/(sx*sx); ivs[2*t+1] = 1.f/(sy*sy);
    }
    xn_s[t] = unmapf(h3m[(size_t)n*64 + t]);
    int e0 = rp3[n], e1 = rp3[n+1], deg = e1 - e0;
    float px = pos3[2*n], py = pos3[2*n+1];
    const int* cols = ei3 + E3;
    float sacc[9] = {0.f,0.f,0.f,0.f,0.f,0.f,0.f,0.f,0.f};
    __syncthreads();
    for (int base = e0; base < e1; base += 64){
        int ne = min(64, e1 - base);
        if (t < ne){
            int j = cols[base + t];
            float ux = (px - pos3[2*j])/SCALE_F + 0.5f;
            float uy = (py - pos3[2*j+1])/SCALE_F + 0.5f;
            #pragma unroll
            for (int k = 0; k < 9; k++){
                float dx = ux - mus[2*k], dy = uy - mus[2*k+1];
                Wc[t*9+k] = expf(-0.5f*(dx*dx*ivs[2*k] + dy*dy*ivs[2*k+1]));
            }
        }
        __syncthreads();
        for (int jj = 0; jj < ne; jj++){
            int j = cols[base + jj];
            float xji = unmapf(h3m[(size_t)j*64 + t]);
            #pragma unroll
            for (int k = 0; k < 9; k++) sacc[k] += xji * Wc[jj*9 + k];
        }
        __syncthreads();
    }
    #pragma unroll
    for (int k = 0; k < 9; k++) S[t*9 + k] = sacc[k];
    __syncthreads();
    float acc = 0.f;
    #pragma unroll 4
    for (int idx = 0; idx < 576; idx++) acc += g3[idx*64 + t] * S[idx];
    float r = 0.f;
    #pragma unroll 4
    for (int ii = 0; ii < 64; ii++) r += xn_s[ii] * rt3[ii*64 + t];
    float h = eluf(acc/(float)max(deg,1) + r + b3[t]);
    atomicAdd(&gsum[t], h);
}

__global__ void final_kernel(const float* __restrict__ gsum, const float* __restrict__ fw,
                             const float* __restrict__ fb, float* __restrict__ out, int C2){
    int p = threadIdx.x; // 128 threads
    float cnt = (float)C2;
    float acc = fb[p];
    for (int o = 0; o < 64; o++) acc += (gsum[o]/cnt) * fw[o*128 + p];
    out[p] = acc;
}

extern "C" void kernel_launch(void* const* d_in, const int* in_sizes, int n_in,
                              void* d_out, int out_size, void* d_ws, size_t ws_size,
                              hipStream_t stream)
{
    const float* x    = (const float*)d_in[0];
    const float* pos  = (const float*)d_in[1];
    const int*   ei1  = (const int*)d_in[2];
    const int*   cl1  = (const int*)d_in[3];
    const int*   ei2  = (const int*)d_in[4];
    const int*   cl2  = (const int*)d_in[5];
    const int*   ei3  = (const int*)d_in[6];
    const float* g1   = (const float*)d_in[8];
    const float* mu1  = (const float*)d_in[9];
    const float* sg1  = (const float*)d_in[10];
    const float* rt1  = (const float*)d_in[11];
    const float* b1   = (const float*)d_in[12];
    const float* g2   = (const float*)d_in[13];
    const float* mu2  = (const float*)d_in[14];
    const float* sg2  = (const float*)d_in[15];
    const float* rt2  = (const float*)d_in[16];
    const float* b2   = (const float*)d_in[17];
    const float* g3   = (const float*)d_in[18];
    const float* mu3  = (const float*)d_in[19];
    const float* sg3  = (const float*)d_in[20];
    const float* rt3  = (const float*)d_in[21];
    const float* b3   = (const float*)d_in[22];
    const float* fw   = (const float*)d_in[23];
    const float* fb   = (const float*)d_in[24];
    float* out = (float*)d_out;

    const int N  = in_sizes[0];
    const int E1 = in_sizes[2] / 2;
    const int C1 = in_sizes[5];
    const int E2 = in_sizes[4] / 2;
    const int C2 = in_sizes[7];
    const int E3 = in_sizes[6] / 2;

    // workspace layout (4-byte units)
    float* w = (float*)d_ws;
    size_t off = 0;
    int* rp1 = (int*)(w + off); off += (size_t)N + 1;
    int* rp2 = (int*)(w + off); off += (size_t)C1 + 1;
    int* rp3 = (int*)(w + off); off += (size_t)C2 + 1;
    unsigned* h2m = (unsigned*)(w + off); off += (size_t)C1 * 32;  // max-region (contiguous)
    unsigned* h3m = (unsigned*)(w + off); off += (size_t)C2 * 64;
    float* pos2  = w + off; off += (size_t)2 * C1;                 // zero-region (contiguous)
    float* cntc1 = w + off; off += (size_t)C1;
    float* pos3  = w + off; off += (size_t)2 * C2;
    float* cntc2 = w + off; off += (size_t)C2;
    float* gsum  = w + off; off += 64;

    const int nmax = C1*32 + C2*64;
    init_max_kernel<<<dim3(256), dim3(256), 0, stream>>>(h2m, nmax);
    hipMemsetAsync(pos2, 0, ((size_t)3*C1 + 3*C2 + 64) * sizeof(float), stream);

    build_rowptr<<<dim3((N + 1 + 255)/256), dim3(256), 0, stream>>>(ei1, E1, N,  rp1);
    build_rowptr<<<dim3((C1 + 1 + 255)/256), dim3(256), 0, stream>>>(ei2, E2, C1, rp2);
    build_rowptr<<<dim3((C2 + 1 + 255)/256), dim3(256), 0, stream>>>(ei3, E3, C2, rp3);

    l1_kernel<<<dim3((N + 255)/256), dim3(256), 0, stream>>>(x, pos, ei1, E1, rp1, cl1,
        g1, mu1, sg1, rt1, b1, h2m, pos2, cntc1, N);
    posdiv_kernel<<<dim3((C1 + 255)/256), dim3(256), 0, stream>>>(pos2, cntc1, C1);
    l2_kernel<<<dim3(C1), dim3(64), 0, stream>>>(h2m, pos2, ei2, E2, rp2, cl2,
        g2, mu2, sg2, rt2, b2, h3m, pos3, cntc2);
    posdiv_kernel<<<dim3((C2 + 255)/256), dim3(256), 0, stream>>>(pos3, cntc2, C2);
    l3_kernel<<<dim3(C2), dim3(64), 0, stream>>>(h3m, pos3, ei3, E3, rp3,
        g3, mu3, sg3, rt3, b3, gsum);
    final_kernel<<<dim3(1), dim3(128), 0, stream>>>(gsum, fw, fb, out, C2);
}

// Round 3
// 246.104 us; speedup vs baseline: 1.7346x; 1.7346x over previous
//
#include <hip/hip_runtime.h>
#include <math.h>

static constexpr float SCALE_F = (float)(2.0 * 28.0 * 0.32178);

// order-preserving float<->uint bijection for atomic max on floats
__device__ __forceinline__ unsigned mapf(float f){
    unsigned u = __float_as_uint(f);
    return (u & 0x80000000u) ? ~u : (u | 0x80000000u);
}
__device__ __forceinline__ float unmapf(unsigned m){
    unsigned u = (m & 0x80000000u) ? (m ^ 0x80000000u) : ~m;
    return __uint_as_float(u);
}
__device__ __forceinline__ float eluf(float x){ return x > 0.f ? x : expm1f(x); }

// init h2m/h3m to mapf(-inf) and zero the sum region — one kernel, no memset dispatch
__global__ void init_all(unsigned* __restrict__ hmax, int nmax, float* __restrict__ zreg, int nz){
    int i = blockIdx.x*blockDim.x + threadIdx.x;
    int s = gridDim.x*blockDim.x;
    for (int k = i; k < nmax; k += s) hmax[k] = 0x007FFFFFu; // mapf(-inf)
    for (int k = i; k < nz;   k += s) zreg[k] = 0.f;
}

// all three rowptr builds in one dispatch. rp[n] = lower_bound(rows, n)
__global__ void build_rowptr_all(const int* __restrict__ r1, int E1, int N1, int* __restrict__ rp1,
                                 const int* __restrict__ r2, int E2, int N2, int* __restrict__ rp2,
                                 const int* __restrict__ r3, int E3, int N3, int* __restrict__ rp3){
    int i = blockIdx.x*blockDim.x + threadIdx.x;
    const int* rows; int E; int n; int* rp;
    if (i <= N1)               { rows=r1; E=E1; n=i;            rp=rp1+n; }
    else if (i <= N1+1+N2)     { rows=r2; E=E2; n=i-(N1+1);     rp=rp2+n; }
    else if (i <= N1+N2+2+N3)  { rows=r3; E=E3; n=i-(N1+N2+2);  rp=rp3+n; }
    else return;
    int lo = 0, hi = E;
    while (lo < hi){ int mid = (lo+hi) >> 1; if (rows[mid] < n) lo = mid+1; else hi = mid; }
    *rp = lo;
}

// Layer 1: I=1, O=32. ONE WAVE PER NODE; lanes parallel over edges; butterfly reduce s[9].
__global__ __launch_bounds__(256) void l1_kernel(const float* __restrict__ x, const float* __restrict__ pos,
    const int* __restrict__ ei1, int E1, const int* __restrict__ rp1, const int* __restrict__ cl1,
    const float* __restrict__ g1, const float* __restrict__ mu1, const float* __restrict__ sg1,
    const float* __restrict__ rt1, const float* __restrict__ b1,
    unsigned* __restrict__ h2m, float* __restrict__ pos2s, float* __restrict__ cntc1, int N)
{
    int wv = threadIdx.x >> 6, lane = threadIdx.x & 63;
    int n = blockIdx.x*4 + wv;
    if (n >= N) return;
    const int* cols = ei1 + E1;
    float mx[9], my[9], ivx[9], ivy[9];
    #pragma unroll
    for (int k = 0; k < 9; k++){
        mx[k] = mu1[2*k]; my[k] = mu1[2*k+1];
        float sx = sg1[2*k], sy = sg1[2*k+1];
        ivx[k] = 1.f/(sx*sx); ivy[k] = 1.f/(sy*sy);
    }
    float px = pos[2*n], py = pos[2*n+1];
    int e0 = rp1[n], e1 = rp1[n+1];
    float s[9] = {0.f,0.f,0.f,0.f,0.f,0.f,0.f,0.f,0.f};
    for (int e = e0 + lane; e < e1; e += 64){
        int j = cols[e];
        float ux = (px - pos[2*j])/SCALE_F + 0.5f;
        float uy = (py - pos[2*j+1])/SCALE_F + 0.5f;
        float xj = x[j];
        #pragma unroll
        for (int k = 0; k < 9; k++){
            float dx = ux - mx[k], dy = uy - my[k];
            s[k] += xj * expf(-0.5f*(dx*dx*ivx[k] + dy*dy*ivy[k]));
        }
    }
    #pragma unroll
    for (int off = 32; off > 0; off >>= 1){
        #pragma unroll
        for (int k = 0; k < 9; k++) s[k] += __shfl_xor(s[k], off, 64);
    }
    float inv = 1.f / (float)max(e1 - e0, 1);
    int c = cl1[n];
    if (lane < 32){
        int o = lane;
        float acc = 0.f;
        #pragma unroll
        for (int k = 0; k < 9; k++) acc += g1[k*32+o] * s[k];
        float v = acc*inv + x[n]*rt1[o] + b1[o];
        atomicMax(&h2m[(size_t)c*32 + o], mapf(eluf(v)));
    }
    if (lane == 0){
        atomicAdd(&pos2s[2*c],   px);
        atomicAdd(&pos2s[2*c+1], py);
        atomicAdd(&cntc1[c], 1.f);
    }
}

// Layer 2: I=32, O=64. One 256-thread block (4 waves, 8 edge-groups) per node.
__global__ __launch_bounds__(256) void l2_kernel(const unsigned* __restrict__ h2m,
    const float* __restrict__ pos2s, const float* __restrict__ cntc1,
    const int* __restrict__ ei2, int E2, const int* __restrict__ rp2, const int* __restrict__ cl2,
    const float* __restrict__ g2, const float* __restrict__ mu2, const float* __restrict__ sg2,
    const float* __restrict__ rt2, const float* __restrict__ b2,
    unsigned* __restrict__ h3m, float* __restrict__ pos3s, float* __restrict__ cntc2)
{
    int n = blockIdx.x, t = threadIdx.x;
    __shared__ float mus[18], ivs[18];
    __shared__ int   jc[64];
    __shared__ float Wc[64*9];
    __shared__ float Sp[8*288];   // [group][i*9+k]
    __shared__ float Ssum[288];
    __shared__ float xn_s[32];
    __shared__ float red1[4*64], red2[4*64];
    if (t < 9){
        mus[2*t] = mu2[2*t]; mus[2*t+1] = mu2[2*t+1];
        float sx = sg2[2*t], sy = sg2[2*t+1];
        ivs[2*t] = 1.f/(sx*sx); ivs[2*t+1] = 1.f/(sy*sy);
    }
    if (t < 32) xn_s[t] = unmapf(h2m[(size_t)n*32 + t]);
    int e0 = rp2[n], e1 = rp2[n+1], deg = e1 - e0;
    float cn = fmaxf(cntc1[n], 1.f);
    float px = pos2s[2*n]/cn, py = pos2s[2*n+1]/cn;   // fused posdiv
    const int* cols = ei2 + E2;
    int i = t & 31, g = t >> 5;
    float sacc[9] = {0.f,0.f,0.f,0.f,0.f,0.f,0.f,0.f,0.f};
    __syncthreads();
    for (int base = e0; base < e1; base += 64){
        int ne = min(64, e1 - base);
        if (t < ne){
            int j = cols[base + t];
            jc[t] = j;
            float cj = fmaxf(cntc1[j], 1.f);
            float ux = (px - pos2s[2*j]/cj)/SCALE_F + 0.5f;
            float uy = (py - pos2s[2*j+1]/cj)/SCALE_F + 0.5f;
            #pragma unroll
            for (int k = 0; k < 9; k++){
                float dx = ux - mus[2*k], dy = uy - mus[2*k+1];
                Wc[t*9+k] = expf(-0.5f*(dx*dx*ivs[2*k] + dy*dy*ivs[2*k+1]));
            }
        }
        __syncthreads();
        for (int jj = g; jj < ne; jj += 8){
            int j = jc[jj];
            float xji = unmapf(h2m[(size_t)j*32 + i]);
            #pragma unroll
            for (int k = 0; k < 9; k++) sacc[k] += xji * Wc[jj*9 + k];
        }
        __syncthreads();
    }
    #pragma unroll
    for (int k = 0; k < 9; k++) Sp[g*288 + i*9 + k] = sacc[k];
    __syncthreads();
    for (int idx = t; idx < 288; idx += 256){
        float v = 0.f;
        #pragma unroll
        for (int gg = 0; gg < 8; gg++) v += Sp[gg*288 + idx];
        Ssum[idx] = v;
    }
    __syncthreads();
    int o = t & 63, p = t >> 6;
    float acc = 0.f;
    for (int idx = p*72; idx < p*72 + 72; idx++) acc += g2[idx*64 + o] * Ssum[idx];
    float racc = 0.f;
    #pragma unroll
    for (int ii = p*8; ii < p*8 + 8; ii++) racc += xn_s[ii] * rt2[ii*64 + o];
    red1[p*64+o] = acc; red2[p*64+o] = racc;
    __syncthreads();
    if (t < 64){
        float agg = red1[t] + red1[64+t] + red1[128+t] + red1[192+t];
        float rr  = red2[t] + red2[64+t] + red2[128+t] + red2[192+t];
        float inv = 1.f / (float)max(deg, 1);
        float h = eluf(agg*inv + rr + b2[t]);
        int c = cl2[n];
        atomicMax(&h3m[(size_t)c*64 + t], mapf(h));
        if (t == 0){
            atomicAdd(&pos3s[2*c],   px);
            atomicAdd(&pos3s[2*c+1], py);
            atomicAdd(&cntc2[c], 1.f);
        }
    }
}

// Layer 3: I=64, O=64. One 256-thread block (4 waves = 4 edge-groups) per node.
__global__ __launch_bounds__(256) void l3_kernel(const unsigned* __restrict__ h3m,
    const float* __restrict__ pos3s, const float* __restrict__ cntc2,
    const int* __restrict__ ei3, int E3, const int* __restrict__ rp3,
    const float* __restrict__ g3, const float* __restrict__ mu3, const float* __restrict__ sg3,
    const float* __restrict__ rt3, const float* __restrict__ b3,
    float* __restrict__ gpart)
{
    int n = blockIdx.x, t = threadIdx.x;
    __shared__ float mus[18], ivs[18];
    __shared__ int   jc[64];
    __shared__ float Wc[64*9];
    __shared__ float Sp[4*576];   // [wave][i*9+k]
    __shared__ float Ssum[576];
    __shared__ float xn_s[64];
    __shared__ float red1[4*64], red2[4*64];
    if (t < 9){
        mus[2*t] = mu3[2*t]; mus[2*t+1] = mu3[2*t+1];
        float sx = sg3[2*t], sy = sg3[2*t+1];
        ivs[2*t] = 1.f/(sx*sx); ivs[2*t+1] = 1.f/(sy*sy);
    }
    if (t < 64) xn_s[t] = unmapf(h3m[(size_t)n*64 + t]);
    int e0 = rp3[n], e1 = rp3[n+1], deg = e1 - e0;
    float cn = fmaxf(cntc2[n], 1.f);
    float px = pos3s[2*n]/cn, py = pos3s[2*n+1]/cn;   // fused posdiv
    const int* cols = ei3 + E3;
    int i = t & 63, wv = t >> 6;
    float sacc[9] = {0.f,0.f,0.f,0.f,0.f,0.f,0.f,0.f,0.f};
    __syncthreads();
    for (int base = e0; base < e1; base += 64){
        int ne = min(64, e1 - base);
        if (t < ne){
            int j = cols[base + t];
            jc[t] = j;
            float cj = fmaxf(cntc2[j], 1.f);
            float ux = (px - pos3s[2*j]/cj)/SCALE_F + 0.5f;
            float uy = (py - pos3s[2*j+1]/cj)/SCALE_F + 0.5f;
            #pragma unroll
            for (int k = 0; k < 9; k++){
                float dx = ux - mus[2*k], dy = uy - mus[2*k+1];
                Wc[t*9+k] = expf(-0.5f*(dx*dx*ivs[2*k] + dy*dy*ivs[2*k+1]));
            }
        }
        __syncthreads();
        for (int jj = wv; jj < ne; jj += 4){
            int j = jc[jj];
            float xji = unmapf(h3m[(size_t)j*64 + i]);
            #pragma unroll
            for (int k = 0; k < 9; k++) sacc[k] += xji * Wc[jj*9 + k];
        }
        __syncthreads();
    }
    #pragma unroll
    for (int k = 0; k < 9; k++) Sp[wv*576 + i*9 + k] = sacc[k];
    __syncthreads();
    for (int idx = t; idx < 576; idx += 256){
        float v = Sp[idx] + Sp[576 + idx] + Sp[1152 + idx] + Sp[1728 + idx];
        Ssum[idx] = v;
    }
    __syncthreads();
    int o = t & 63, p = t >> 6;
    float acc = 0.f;
    for (int idx = p*144; idx < p*144 + 144; idx++) acc += g3[idx*64 + o] * Ssum[idx];
    float racc = 0.f;
    #pragma unroll
    for (int ii = p*16; ii < p*16 + 16; ii++) racc += xn_s[ii] * rt3[ii*64 + o];
    red1[p*64+o] = acc; red2[p*64+o] = racc;
    __syncthreads();
    if (t < 64){
        float agg = red1[t] + red1[64+t] + red1[128+t] + red1[192+t];
        float rr  = red2[t] + red2[64+t] + red2[128+t] + red2[192+t];
        float inv = 1.f / (float)max(deg, 1);
        float h = eluf(agg*inv + rr + b3[t]);
        atomicAdd(&gpart[(size_t)(n & 63)*64 + t], h);  // 64-slot partials: low contention
    }
}

__global__ void final_kernel(const float* __restrict__ gpart, const float* __restrict__ fw,
                             const float* __restrict__ fb, float* __restrict__ out, int C2){
    __shared__ float gs[64];
    __shared__ float red[2*64];
    int t = threadIdx.x;           // 128 threads
    int o = t & 63, h = t >> 6;
    float a = 0.f;
    for (int p = h*32; p < h*32 + 32; p++) a += gpart[p*64 + o];
    red[h*64 + o] = a;
    __syncthreads();
    if (t < 64) gs[t] = (red[t] + red[64+t]) / (float)C2;
    __syncthreads();
    float acc = fb[t];
    for (int o2 = 0; o2 < 64; o2++) acc += gs[o2] * fw[o2*128 + t];
    out[t] = acc;
}

extern "C" void kernel_launch(void* const* d_in, const int* in_sizes, int n_in,
                              void* d_out, int out_size, void* d_ws, size_t ws_size,
                              hipStream_t stream)
{
    const float* x    = (const float*)d_in[0];
    const float* pos  = (const float*)d_in[1];
    const int*   ei1  = (const int*)d_in[2];
    const int*   cl1  = (const int*)d_in[3];
    const int*   ei2  = (const int*)d_in[4];
    const int*   cl2  = (const int*)d_in[5];
    const int*   ei3  = (const int*)d_in[6];
    const float* g1   = (const float*)d_in[8];
    const float* mu1  = (const float*)d_in[9];
    const float* sg1  = (const float*)d_in[10];
    const float* rt1  = (const float*)d_in[11];
    const float* b1   = (const float*)d_in[12];
    const float* g2   = (const float*)d_in[13];
    const float* mu2  = (const float*)d_in[14];
    const float* sg2  = (const float*)d_in[15];
    const float* rt2  = (const float*)d_in[16];
    const float* b2   = (const float*)d_in[17];
    const float* g3   = (const float*)d_in[18];
    const float* mu3  = (const float*)d_in[19];
    const float* sg3  = (const float*)d_in[20];
    const float* rt3  = (const float*)d_in[21];
    const float* b3   = (const float*)d_in[22];
    const float* fw   = (const float*)d_in[23];
    const float* fb   = (const float*)d_in[24];
    float* out = (float*)d_out;

    const int N  = in_sizes[0];
    const int E1 = in_sizes[2] / 2;
    const int C1 = in_sizes[5];
    const int E2 = in_sizes[4] / 2;
    const int C2 = in_sizes[7];
    const int E3 = in_sizes[6] / 2;

    // workspace layout (4-byte units)
    float* w = (float*)d_ws;
    size_t off = 0;
    int* rp1 = (int*)(w + off); off += (size_t)N + 1;
    int* rp2 = (int*)(w + off); off += (size_t)C1 + 1;
    int* rp3 = (int*)(w + off); off += (size_t)C2 + 1;
    unsigned* h2m = (unsigned*)(w + off); off += (size_t)C1 * 32;  // max-region (contiguous)
    unsigned* h3m = (unsigned*)(w + off); off += (size_t)C2 * 64;
    float* pos2s = w + off; off += (size_t)2 * C1;                 // zero-region (contiguous)
    float* cntc1 = w + off; off += (size_t)C1;
    float* pos3s = w + off; off += (size_t)2 * C2;
    float* cntc2 = w + off; off += (size_t)C2;
    float* gpart = w + off; off += 64*64;

    const int nmax = C1*32 + C2*64;
    const int nz   = 3*C1 + 3*C2 + 64*64;
    init_all<<<dim3(256), dim3(256), 0, stream>>>(h2m, nmax, pos2s, nz);

    int nrp = N + C1 + C2 + 3;
    build_rowptr_all<<<dim3((nrp + 255)/256), dim3(256), 0, stream>>>(
        ei1, E1, N, rp1, ei2, E2, C1, rp2, ei3, E3, C2, rp3);

    l1_kernel<<<dim3((N + 3)/4), dim3(256), 0, stream>>>(x, pos, ei1, E1, rp1, cl1,
        g1, mu1, sg1, rt1, b1, h2m, pos2s, cntc1, N);
    l2_kernel<<<dim3(C1), dim3(256), 0, stream>>>(h2m, pos2s, cntc1, ei2, E2, rp2, cl2,
        g2, mu2, sg2, rt2, b2, h3m, pos3s, cntc2);
    l3_kernel<<<dim3(C2), dim3(256), 0, stream>>>(h3m, pos3s, cntc2, ei3, E3, rp3,
        g3, mu3, sg3, rt3, b3, gpart);
    final_kernel<<<dim3(1), dim3(128), 0, stream>>>(gpart, fw, fb, out, C2);
}

// Round 6
// 229.227 us; speedup vs baseline: 1.8623x; 1.0736x over previous
//
#include <hip/hip_runtime.h>
#include <math.h>

static constexpr float SCALE_F = (float)(2.0 * 28.0 * 0.32178);

// order-preserving float<->uint bijection for atomic max on floats
__device__ __forceinline__ unsigned mapf(float f){
    unsigned u = __float_as_uint(f);
    return (u & 0x80000000u) ? ~u : (u | 0x80000000u);
}
__device__ __forceinline__ float unmapf(unsigned m){
    unsigned u = (m & 0x80000000u) ? (m ^ 0x80000000u) : ~m;
    return __uint_as_float(u);
}
__device__ __forceinline__ float eluf(float x){ return x > 0.f ? x : expm1f(x); }

// Wave-local LDS visibility: lockstep wave + drain LDS queue. No s_barrier, so
// per-wave loops with differing trip counts are safe (block barriers would deadlock).
__device__ __forceinline__ void wave_sync(){
    __builtin_amdgcn_wave_barrier();
    asm volatile("s_waitcnt lgkmcnt(0)" ::: "memory");
    __builtin_amdgcn_wave_barrier();
}

// prep: init max-regions, zero sum-regions, pack {pos,x} float4, build 3 rowptrs. 1 dispatch.
__global__ void prep_kernel(const float* __restrict__ x, const float* __restrict__ pos, int N,
    const int* __restrict__ ei1, int E1, const int* __restrict__ ei2, int E2, int C1,
    const int* __restrict__ ei3, int E3, int C2,
    int* __restrict__ rp1, int* __restrict__ rp2, int* __restrict__ rp3,
    unsigned* __restrict__ hmax, int nmax, float* __restrict__ zreg, int nz,
    float4* __restrict__ xp1)
{
    int i0 = blockIdx.x*blockDim.x + threadIdx.x, gs = gridDim.x*blockDim.x;
    for (int i = i0; i < nmax; i += gs) hmax[i] = 0x007FFFFFu;  // mapf(-inf)
    for (int i = i0; i < nz;   i += gs) zreg[i] = 0.f;
    for (int i = i0; i < N;    i += gs) xp1[i] = make_float4(pos[2*i], pos[2*i+1], x[i], 0.f);
    int nrp = N + C1 + C2 + 3;
    for (int i = i0; i < nrp; i += gs){
        const int* rows; int E, n; int* rp;
        if (i <= N)            { rows = ei1; E = E1; n = i;            rp = rp1 + n; }
        else if (i <= N+1+C1)  { rows = ei2; E = E2; n = i - (N+1);    rp = rp2 + n; }
        else                   { rows = ei3; E = E3; n = i - (N+C1+2); rp = rp3 + n; }
        int lo = 0, hi = E;
        while (lo < hi){ int m = (lo+hi) >> 1; if (rows[m] < n) lo = m+1; else hi = m; }
        *rp = lo;
    }
}

// Layer 1: I=1, O=32. QUARTER-WAVE (16 lanes) per node; 16 nodes per 256-block. No barriers.
__global__ __launch_bounds__(256) void l1_kernel(const float4* __restrict__ xp1,
    const int* __restrict__ ei1, int E1, const int* __restrict__ rp1, const int* __restrict__ cl1,
    const float* __restrict__ g1, const float* __restrict__ mu1, const float* __restrict__ sg1,
    const float* __restrict__ rt1, const float* __restrict__ b1,
    unsigned* __restrict__ h2m, float4* __restrict__ pos2s4, int N)
{
    int t = threadIdx.x;
    int lane = t & 63, wv = t >> 6;
    int q = lane >> 4, il = lane & 15;
    int n = (blockIdx.x*4 + wv)*4 + q;
    if (n >= N) return;
    const int* cols = ei1 + E1;
    float mx[9], my[9], ivx[9], ivy[9];
    #pragma unroll
    for (int k = 0; k < 9; k++){
        mx[k] = mu1[2*k]; my[k] = mu1[2*k+1];
        float sx = sg1[2*k], sy = sg1[2*k+1];
        ivx[k] = 1.f/(sx*sx); ivy[k] = 1.f/(sy*sy);
    }
    float4 me = xp1[n];
    float px = me.x, py = me.y, xn = me.z;
    int e0 = rp1[n], e1 = rp1[n+1];
    float s[9] = {0.f,0.f,0.f,0.f,0.f,0.f,0.f,0.f,0.f};
    for (int e = e0 + il; e < e1; e += 16){
        int j = cols[e];
        float4 pj = xp1[j];
        float ux = (px - pj.x)/SCALE_F + 0.5f;
        float uy = (py - pj.y)/SCALE_F + 0.5f;
        #pragma unroll
        for (int k = 0; k < 9; k++){
            float dx = ux - mx[k], dy = uy - my[k];
            s[k] += pj.z * expf(-0.5f*(dx*dx*ivx[k] + dy*dy*ivy[k]));
        }
    }
    #pragma unroll
    for (int off = 8; off > 0; off >>= 1){
        #pragma unroll
        for (int k = 0; k < 9; k++) s[k] += __shfl_xor(s[k], off, 16);
    }
    float inv = 1.f / (float)max(e1 - e0, 1);
    int c = cl1[n];
    #pragma unroll
    for (int oo = 0; oo < 2; oo++){
        int o = il + oo*16;
        float acc = 0.f;
        #pragma unroll
        for (int k = 0; k < 9; k++) acc += g1[k*32+o] * s[k];
        float v = acc*inv + xn*rt1[o] + b1[o];
        atomicMax(&h2m[(size_t)c*32 + o], mapf(eluf(v)));
    }
    if (il == 0){
        atomicAdd(&pos2s4[c].x, px);
        atomicAdd(&pos2s4[c].y, py);
        atomicAdd(&pos2s4[c].z, 1.f);
    }
}

// Layer 2: I=32, O=64. ONE WAVE PER NODE, 4 nodes/block, ZERO block barriers.
__global__ __launch_bounds__(256) void l2_kernel(const unsigned* __restrict__ h2m,
    const float4* __restrict__ pos2s4,
    const int* __restrict__ ei2, int E2, const int* __restrict__ rp2, const int* __restrict__ cl2,
    const float* __restrict__ g2, const float* __restrict__ mu2, const float* __restrict__ sg2,
    const float* __restrict__ rt2, const float* __restrict__ b2,
    unsigned* __restrict__ h3m, float4* __restrict__ pos3s4, int C1)
{
    __shared__ float wbuf[4][576];   // per-wave: Wc[64][9] during gather, then Ssum[288]
    __shared__ int   jcs[4][64];
    __shared__ float xns[4][32];
    int t = threadIdx.x, l = t & 63, w = t >> 6;
    int n = blockIdx.x*4 + w;
    if (n >= C1) return;
    const int* cols = ei2 + E2;
    float mx[9], my[9], ivx[9], ivy[9];
    #pragma unroll
    for (int k = 0; k < 9; k++){
        mx[k] = mu2[2*k]; my[k] = mu2[2*k+1];
        float sx = sg2[2*k], sy = sg2[2*k+1];
        ivx[k] = 1.f/(sx*sx); ivy[k] = 1.f/(sy*sy);
    }
    if (l < 32) xns[w][l] = unmapf(h2m[(size_t)n*32 + l]);
    float4 pm = pos2s4[n];
    float cn = fmaxf(pm.z, 1.f);
    float px = pm.x/cn, py = pm.y/cn;
    int e0 = rp2[n], e1 = rp2[n+1], deg = e1 - e0;
    int i = l & 31, half = l >> 5;
    float sacc[9] = {0.f,0.f,0.f,0.f,0.f,0.f,0.f,0.f,0.f};
    for (int base = e0; base < e1; base += 64){
        int ne = min(64, e1 - base);
        if (l < ne){
            int j = cols[base + l];
            jcs[w][l] = j;
            float4 pj = pos2s4[j];
            float cj = fmaxf(pj.z, 1.f);
            float ux = (px - pj.x/cj)/SCALE_F + 0.5f;
            float uy = (py - pj.y/cj)/SCALE_F + 0.5f;
            #pragma unroll
            for (int k = 0; k < 9; k++){
                float dx = ux - mx[k], dy = uy - my[k];
                wbuf[w][l*9+k] = expf(-0.5f*(dx*dx*ivx[k] + dy*dy*ivy[k]));
            }
        }
        wave_sync();
        for (int jj = half; jj < ne; jj += 2){
            int j = jcs[w][jj];
            float xji = unmapf(h2m[(size_t)j*32 + i]);
            #pragma unroll
            for (int k = 0; k < 9; k++) sacc[k] += xji * wbuf[w][jj*9+k];
        }
        wave_sync();
    }
    #pragma unroll
    for (int k = 0; k < 9; k++) sacc[k] += __shfl_xor(sacc[k], 32, 64);
    if (l < 32){
        #pragma unroll
        for (int k = 0; k < 9; k++) wbuf[w][l*9+k] = sacc[k];  // Ssum overwrites Wc
    }
    wave_sync();
    float acc = 0.f;
    #pragma unroll 8
    for (int idx = 0; idx < 288; idx++) acc += g2[idx*64 + l] * wbuf[w][idx];
    float racc = 0.f;
    #pragma unroll 8
    for (int ii = 0; ii < 32; ii++) racc += xns[w][ii] * rt2[ii*64 + l];
    float inv = 1.f / (float)max(deg, 1);
    float h = eluf(acc*inv + racc + b2[l]);
    int c = cl2[n];
    atomicMax(&h3m[(size_t)c*64 + l], mapf(h));
    if (l == 0){
        atomicAdd(&pos3s4[c].x, px);
        atomicAdd(&pos3s4[c].y, py);
        atomicAdd(&pos3s4[c].z, 1.f);
    }
}

// Layer 3: I=64, O=64. ONE WAVE PER NODE, 4 nodes/block, ZERO block barriers.
__global__ __launch_bounds__(256) void l3_kernel(const unsigned* __restrict__ h3m,
    const float4* __restrict__ pos3s4,
    const int* __restrict__ ei3, int E3, const int* __restrict__ rp3,
    const float* __restrict__ g3, const float* __restrict__ mu3, const float* __restrict__ sg3,
    const float* __restrict__ rt3, const float* __restrict__ b3,
    float* __restrict__ gpart, int C2)
{
    __shared__ float wbuf[4][576];   // per-wave: Wc[64][9] during gather, then Ssum[576]
    __shared__ int   jcs[4][64];
    __shared__ float xns[4][64];
    int t = threadIdx.x, l = t & 63, w = t >> 6;
    int n = blockIdx.x*4 + w;
    if (n >= C2) return;
    const int* cols = ei3 + E3;
    float mx[9], my[9], ivx[9], ivy[9];
    #pragma unroll
    for (int k = 0; k < 9; k++){
        mx[k] = mu3[2*k]; my[k] = mu3[2*k+1];
        float sx = sg3[2*k], sy = sg3[2*k+1];
        ivx[k] = 1.f/(sx*sx); ivy[k] = 1.f/(sy*sy);
    }
    xns[w][l] = unmapf(h3m[(size_t)n*64 + l]);
    float4 pm = pos3s4[n];
    float cn = fmaxf(pm.z, 1.f);
    float px = pm.x/cn, py = pm.y/cn;
    int e0 = rp3[n], e1 = rp3[n+1], deg = e1 - e0;
    float sacc[9] = {0.f,0.f,0.f,0.f,0.f,0.f,0.f,0.f,0.f};
    for (int base = e0; base < e1; base += 64){
        int ne = min(64, e1 - base);
        if (l < ne){
            int j = cols[base + l];
            jcs[w][l] = j;
            float4 pj = pos3s4[j];
            float cj = fmaxf(pj.z, 1.f);
            float ux = (px - pj.x/cj)/SCALE_F + 0.5f;
            float uy = (py - pj.y/cj)/SCALE_F + 0.5f;
            #pragma unroll
            for (int k = 0; k < 9; k++){
                float dx = ux - mx[k], dy = uy - my[k];
                wbuf[w][l*9+k] = expf(-0.5f*(dx*dx*ivx[k] + dy*dy*ivy[k]));
            }
        }
        wave_sync();
        for (int jj = 0; jj < ne; jj++){
            int j = jcs[w][jj];
            float xji = unmapf(h3m[(size_t)j*64 + l]);
            #pragma unroll
            for (int k = 0; k < 9; k++) sacc[k] += xji * wbuf[w][jj*9+k];
        }
        wave_sync();
    }
    #pragma unroll
    for (int k = 0; k < 9; k++) wbuf[w][l*9+k] = sacc[k];  // Ssum[i*9+k], i=l
    wave_sync();
    float acc = 0.f;
    #pragma unroll 8
    for (int idx = 0; idx < 576; idx++) acc += g3[idx*64 + l] * wbuf[w][idx];
    float racc = 0.f;
    #pragma unroll 8
    for (int ii = 0; ii < 64; ii++) racc += xns[w][ii] * rt3[ii*64 + l];
    float inv = 1.f / (float)max(deg, 1);
    float h = eluf(acc*inv + racc + b3[l]);
    atomicAdd(&gpart[(size_t)(n & 63)*64 + l], h);
}

__global__ void final_kernel(const float* __restrict__ gpart, const float* __restrict__ fw,
                             const float* __restrict__ fb, float* __restrict__ out, int C2){
    __shared__ float gs[64];
    __shared__ float red[2*64];
    int t = threadIdx.x;           // 128 threads
    int o = t & 63, h = t >> 6;
    float a = 0.f;
    for (int p = h*32; p < h*32 + 32; p++) a += gpart[p*64 + o];
    red[h*64 + o] = a;
    __syncthreads();
    if (t < 64) gs[t] = (red[t] + red[64+t]) / (float)C2;
    __syncthreads();
    float acc = fb[t];
    for (int o2 = 0; o2 < 64; o2++) acc += gs[o2] * fw[o2*128 + t];
    out[t] = acc;
}

extern "C" void kernel_launch(void* const* d_in, const int* in_sizes, int n_in,
                              void* d_out, int out_size, void* d_ws, size_t ws_size,
                              hipStream_t stream)
{
    const float* x    = (const float*)d_in[0];
    const float* pos  = (const float*)d_in[1];
    const int*   ei1  = (const int*)d_in[2];
    const int*   cl1  = (const int*)d_in[3];
    const int*   ei2  = (const int*)d_in[4];
    const int*   cl2  = (const int*)d_in[5];
    const int*   ei3  = (const int*)d_in[6];
    const float* g1   = (const float*)d_in[8];
    const float* mu1  = (const float*)d_in[9];
    const float* sg1  = (const float*)d_in[10];
    const float* rt1  = (const float*)d_in[11];
    const float* b1   = (const float*)d_in[12];
    const float* g2   = (const float*)d_in[13];
    const float* mu2  = (const float*)d_in[14];
    const float* sg2  = (const float*)d_in[15];
    const float* rt2  = (const float*)d_in[16];
    const float* b2   = (const float*)d_in[17];
    const float* g3   = (const float*)d_in[18];
    const float* mu3  = (const float*)d_in[19];
    const float* sg3  = (const float*)d_in[20];
    const float* rt3  = (const float*)d_in[21];
    const float* b3   = (const float*)d_in[22];
    const float* fw   = (const float*)d_in[23];
    const float* fb   = (const float*)d_in[24];
    float* out = (float*)d_out;

    const int N  = in_sizes[0];
    const int E1 = in_sizes[2] / 2;
    const int C1 = in_sizes[5];
    const int E2 = in_sizes[4] / 2;
    const int C2 = in_sizes[7];
    const int E3 = in_sizes[6] / 2;

    // workspace layout (float4 arrays first for 16B alignment; counts are multiples of 4)
    float* w = (float*)d_ws;
    size_t off = 0;
    float4* xp1    = (float4*)(w + off); off += (size_t)4*N;
    float4* pos2s4 = (float4*)(w + off); off += (size_t)4*C1;   // zero-region start
    float4* pos3s4 = (float4*)(w + off); off += (size_t)4*C2;
    float*  gpart  = w + off;            off += 64*64;
    int* rp1 = (int*)(w + off); off += (size_t)N + 1;
    int* rp2 = (int*)(w + off); off += (size_t)C1 + 1;
    int* rp3 = (int*)(w + off); off += (size_t)C2 + 1;
    unsigned* h2m = (unsigned*)(w + off); off += (size_t)C1 * 32;  // max-region (contiguous)
    unsigned* h3m = (unsigned*)(w + off); off += (size_t)C2 * 64;

    const int nmax = C1*32 + C2*64;
    const int nz   = 4*C1 + 4*C2 + 64*64;
    prep_kernel<<<dim3(1024), dim3(256), 0, stream>>>(x, pos, N,
        ei1, E1, ei2, E2, C1, ei3, E3, C2,
        rp1, rp2, rp3, h2m, nmax, (float*)pos2s4, nz, xp1);

    l1_kernel<<<dim3((N + 15)/16), dim3(256), 0, stream>>>(xp1, ei1, E1, rp1, cl1,
        g1, mu1, sg1, rt1, b1, h2m, pos2s4, N);
    l2_kernel<<<dim3((C1 + 3)/4), dim3(256), 0, stream>>>(h2m, pos2s4, ei2, E2, rp2, cl2,
        g2, mu2, sg2, rt2, b2, h3m, pos3s4, C1);
    l3_kernel<<<dim3((C2 + 3)/4), dim3(256), 0, stream>>>(h3m, pos3s4, ei3, E3, rp3,
        g3, mu3, sg3, rt3, b3, gpart, C2);
    final_kernel<<<dim3(1), dim3(128), 0, stream>>>(gpart, fw, fb, out, C2);
}

// Round 8
// 220.113 us; speedup vs baseline: 1.9394x; 1.0414x over previous
//
#include <hip/hip_runtime.h>
#include <math.h>

static constexpr float SCALE_F = (float)(2.0 * 28.0 * 0.32178);

// order-preserving float<->uint bijection for atomic max on floats
__device__ __forceinline__ unsigned mapf(float f){
    unsigned u = __float_as_uint(f);
    return (u & 0x80000000u) ? ~u : (u | 0x80000000u);
}
__device__ __forceinline__ float unmapf(unsigned m){
    unsigned u = (m & 0x80000000u) ? (m ^ 0x80000000u) : ~m;
    return __uint_as_float(u);
}
__device__ __forceinline__ float eluf(float x){ return x > 0.f ? x : expm1f(x); }

// Wave-local LDS visibility: lockstep wave + drain LDS queue. Used ONLY in the
// variable-trip gather phase (wave-private data); uniform phases use __syncthreads.
__device__ __forceinline__ void wave_sync(){
    __builtin_amdgcn_wave_barrier();
    asm volatile("s_waitcnt lgkmcnt(0)" ::: "memory");
    __builtin_amdgcn_wave_barrier();
}

// prep: init max-regions, zero sum-regions, pack {pos,x} float4, build 3 rowptrs. 1 dispatch.
__global__ void prep_kernel(const float* __restrict__ x, const float* __restrict__ pos, int N,
    const int* __restrict__ ei1, int E1, const int* __restrict__ ei2, int E2, int C1,
    const int* __restrict__ ei3, int E3, int C2,
    int* __restrict__ rp1, int* __restrict__ rp2, int* __restrict__ rp3,
    unsigned* __restrict__ hmax, int nmax, float* __restrict__ zreg, int nz,
    float4* __restrict__ xp1)
{
    int i0 = blockIdx.x*blockDim.x + threadIdx.x, gs = gridDim.x*blockDim.x;
    for (int i = i0; i < nmax; i += gs) hmax[i] = 0x007FFFFFu;  // mapf(-inf)
    for (int i = i0; i < nz;   i += gs) zreg[i] = 0.f;
    for (int i = i0; i < N;    i += gs) xp1[i] = make_float4(pos[2*i], pos[2*i+1], x[i], 0.f);
    int nrp = N + C1 + C2 + 3;
    for (int i = i0; i < nrp; i += gs){
        const int* rows; int E, n; int* rp;
        if (i <= N)            { rows = ei1; E = E1; n = i;            rp = rp1 + n; }
        else if (i <= N+1+C1)  { rows = ei2; E = E2; n = i - (N+1);    rp = rp2 + n; }
        else                   { rows = ei3; E = E3; n = i - (N+C1+2); rp = rp3 + n; }
        int lo = 0, hi = E;
        while (lo < hi){ int m = (lo+hi) >> 1; if (rows[m] < n) lo = m+1; else hi = m; }
        *rp = lo;
    }
}

// Layer 1: I=1, O=32. QUARTER-WAVE (16 lanes) per node; 16 nodes per 256-block. No barriers.
__global__ __launch_bounds__(256) void l1_kernel(const float4* __restrict__ xp1,
    const int* __restrict__ ei1, int E1, const int* __restrict__ rp1, const int* __restrict__ cl1,
    const float* __restrict__ g1, const float* __restrict__ mu1, const float* __restrict__ sg1,
    const float* __restrict__ rt1, const float* __restrict__ b1,
    unsigned* __restrict__ h2m, float4* __restrict__ pos2s4, int N)
{
    int t = threadIdx.x;
    int lane = t & 63, wv = t >> 6;
    int q = lane >> 4, il = lane & 15;
    int n = (blockIdx.x*4 + wv)*4 + q;
    if (n >= N) return;
    const int* cols = ei1 + E1;
    float mx[9], my[9], ivx[9], ivy[9];
    #pragma unroll
    for (int k = 0; k < 9; k++){
        mx[k] = mu1[2*k]; my[k] = mu1[2*k+1];
        float sx = sg1[2*k], sy = sg1[2*k+1];
        ivx[k] = 1.f/(sx*sx); ivy[k] = 1.f/(sy*sy);
    }
    float4 me = xp1[n];
    float px = me.x, py = me.y, xn = me.z;
    int e0 = rp1[n], e1 = rp1[n+1];
    float s[9] = {0.f,0.f,0.f,0.f,0.f,0.f,0.f,0.f,0.f};
    for (int e = e0 + il; e < e1; e += 16){
        int j = cols[e];
        float4 pj = xp1[j];
        float ux = (px - pj.x)/SCALE_F + 0.5f;
        float uy = (py - pj.y)/SCALE_F + 0.5f;
        #pragma unroll
        for (int k = 0; k < 9; k++){
            float dx = ux - mx[k], dy = uy - my[k];
            s[k] += pj.z * expf(-0.5f*(dx*dx*ivx[k] + dy*dy*ivy[k]));
        }
    }
    #pragma unroll
    for (int off = 8; off > 0; off >>= 1){
        #pragma unroll
        for (int k = 0; k < 9; k++) s[k] += __shfl_xor(s[k], off, 16);
    }
    float inv = 1.f / (float)max(e1 - e0, 1);
    int c = cl1[n];
    #pragma unroll
    for (int oo = 0; oo < 2; oo++){
        int o = il + oo*16;
        float acc = 0.f;
        #pragma unroll
        for (int k = 0; k < 9; k++) acc += g1[k*32+o] * s[k];
        float v = acc*inv + xn*rt1[o] + b1[o];
        atomicMax(&h2m[(size_t)c*32 + o], mapf(eluf(v)));
    }
    if (il == 0){
        atomicAdd(&pos2s4[c].x, px);
        atomicAdd(&pos2s4[c].y, py);
        atomicAdd(&pos2s4[c].z, 1.f);
    }
}

// Layer 2: I=32, O=64. Wave-per-node gather (no block barriers), then LOCKSTEP
// LDS-staged tiled contraction: g2 staged in 32x64 tiles shared by all 4 waves.
__global__ __launch_bounds__(256) void l2_kernel(const unsigned* __restrict__ h2m,
    const float4* __restrict__ pos2s4,
    const int* __restrict__ ei2, int E2, const int* __restrict__ rp2, const int* __restrict__ cl2,
    const float* __restrict__ g2, const float* __restrict__ mu2, const float* __restrict__ sg2,
    const float* __restrict__ rt2, const float* __restrict__ b2,
    unsigned* __restrict__ h3m, float4* __restrict__ pos3s4, int C1)
{
    __shared__ float wbuf[4][576];   // per-wave: Wc[64][9] during gather, then Ssum[288]
    __shared__ int   jcs[4][64];
    __shared__ float xns[4][32];
    __shared__ float gt[32*64];      // staged g2/rt2 tile (8 KB)
    int t = threadIdx.x, l = t & 63, w = t >> 6;
    int n0 = blockIdx.x*4 + w;
    int n = min(n0, C1-1);
    bool active = (n0 < C1);
    const int* cols = ei2 + E2;
    float mx[9], my[9], ivx[9], ivy[9];
    #pragma unroll
    for (int k = 0; k < 9; k++){
        mx[k] = mu2[2*k]; my[k] = mu2[2*k+1];
        float sx = sg2[2*k], sy = sg2[2*k+1];
        ivx[k] = 1.f/(sx*sx); ivy[k] = 1.f/(sy*sy);
    }
    if (l < 32) xns[w][l] = unmapf(h2m[(size_t)n*32 + l]);
    float4 pm = pos2s4[n];
    float cn = fmaxf(pm.z, 1.f);
    float px = pm.x/cn, py = pm.y/cn;
    int e0 = rp2[n], e1 = rp2[n+1], deg = e1 - e0;
    int i = l & 31, half = l >> 5;
    float sacc[9] = {0.f,0.f,0.f,0.f,0.f,0.f,0.f,0.f,0.f};
    for (int base = e0; base < e1; base += 64){
        int ne = min(64, e1 - base);
        if (l < ne){
            int j = cols[base + l];
            jcs[w][l] = j;
            float4 pj = pos2s4[j];
            float cj = fmaxf(pj.z, 1.f);
            float ux = (px - pj.x/cj)/SCALE_F + 0.5f;
            float uy = (py - pj.y/cj)/SCALE_F + 0.5f;
            #pragma unroll
            for (int k = 0; k < 9; k++){
                float dx = ux - mx[k], dy = uy - my[k];
                wbuf[w][l*9+k] = expf(-0.5f*(dx*dx*ivx[k] + dy*dy*ivy[k]));
            }
        }
        wave_sync();
        for (int jj = half; jj < ne; jj += 2){
            int j = jcs[w][jj];
            float xji = unmapf(h2m[(size_t)j*32 + i]);
            #pragma unroll
            for (int k = 0; k < 9; k++) sacc[k] += xji * wbuf[w][jj*9+k];
        }
        wave_sync();
    }
    #pragma unroll
    for (int k = 0; k < 9; k++) sacc[k] += __shfl_xor(sacc[k], 32, 64);
    if (l < 32){
        #pragma unroll
        for (int k = 0; k < 9; k++) wbuf[w][l*9+k] = sacc[k];  // Ssum[0..287] overwrites Wc
    }
    // ---- lockstep tiled contraction: 9 tiles of g2 (32x64) + 1 root tile (rt2, 32x64)
    float acc = 0.f, racc = 0.f;
    for (int tile = 0; tile < 10; tile++){
        __syncthreads();
        const float4* src = (tile < 9) ? (const float4*)(g2 + tile*2048) : (const float4*)rt2;
        float4* dst = (float4*)gt;
        #pragma unroll
        for (int r = 0; r < 2; r++) dst[t + 256*r] = src[t + 256*r];
        __syncthreads();
        if (tile < 9){
            #pragma unroll 8
            for (int ii = 0; ii < 32; ii++) acc += gt[ii*64 + l] * wbuf[w][tile*32 + ii];
        } else {
            #pragma unroll 8
            for (int ii = 0; ii < 32; ii++) racc += gt[ii*64 + l] * xns[w][ii];
        }
    }
    float inv = 1.f / (float)max(deg, 1);
    float h = eluf(acc*inv + racc + b2[l]);
    if (active){
        int c = cl2[n];
        atomicMax(&h3m[(size_t)c*64 + l], mapf(h));
        if (l == 0){
            atomicAdd(&pos3s4[c].x, px);
            atomicAdd(&pos3s4[c].y, py);
            atomicAdd(&pos3s4[c].z, 1.f);
        }
    }
}

// Layer 3: I=64, O=64. Wave-per-node gather, then LOCKSTEP LDS-staged tiled
// contraction: g3 staged in 64x64 tiles shared by all 4 waves.
__global__ __launch_bounds__(256) void l3_kernel(const unsigned* __restrict__ h3m,
    const float4* __restrict__ pos3s4,
    const int* __restrict__ ei3, int E3, const int* __restrict__ rp3,
    const float* __restrict__ g3, const float* __restrict__ mu3, const float* __restrict__ sg3,
    const float* __restrict__ rt3, const float* __restrict__ b3,
    float* __restrict__ gpart, int C2)
{
    __shared__ float wbuf[4][576];   // per-wave: Wc[64][9] during gather, then Ssum[576]
    __shared__ int   jcs[4][64];
    __shared__ float xns[4][64];
    __shared__ float gt[64*64];      // staged g3/rt3 tile (16 KB)
    int t = threadIdx.x, l = t & 63, w = t >> 6;
    int n0 = blockIdx.x*4 + w;
    int n = min(n0, C2-1);
    bool active = (n0 < C2);
    const int* cols = ei3 + E3;
    float mx[9], my[9], ivx[9], ivy[9];
    #pragma unroll
    for (int k = 0; k < 9; k++){
        mx[k] = mu3[2*k]; my[k] = mu3[2*k+1];
        float sx = sg3[2*k], sy = sg3[2*k+1];
        ivx[k] = 1.f/(sx*sx); ivy[k] = 1.f/(sy*sy);
    }
    xns[w][l] = unmapf(h3m[(size_t)n*64 + l]);
    float4 pm = pos3s4[n];
    float cn = fmaxf(pm.z, 1.f);
    float px = pm.x/cn, py = pm.y/cn;
    int e0 = rp3[n], e1 = rp3[n+1], deg = e1 - e0;
    float sacc[9] = {0.f,0.f,0.f,0.f,0.f,0.f,0.f,0.f,0.f};
    for (int base = e0; base < e1; base += 64){
        int ne = min(64, e1 - base);
        if (l < ne){
            int j = cols[base + l];
            jcs[w][l] = j;
            float4 pj = pos3s4[j];
            float cj = fmaxf(pj.z, 1.f);
            float ux = (px - pj.x/cj)/SCALE_F + 0.5f;
            float uy = (py - pj.y/cj)/SCALE_F + 0.5f;
            #pragma unroll
            for (int k = 0; k < 9; k++){
                float dx = ux - mx[k], dy = uy - my[k];
                wbuf[w][l*9+k] = expf(-0.5f*(dx*dx*ivx[k] + dy*dy*ivy[k]));
            }
        }
        wave_sync();
        for (int jj = 0; jj < ne; jj++){
            int j = jcs[w][jj];
            float xji = unmapf(h3m[(size_t)j*64 + l]);
            #pragma unroll
            for (int k = 0; k < 9; k++) sacc[k] += xji * wbuf[w][jj*9+k];
        }
        wave_sync();
    }
    #pragma unroll
    for (int k = 0; k < 9; k++) wbuf[w][l*9+k] = sacc[k];  // Ssum[i*9+k], i=l
    // ---- lockstep tiled contraction: 9 tiles of g3 (64x64) + 1 root tile (rt3, 64x64)
    float acc = 0.f, racc = 0.f;
    for (int tile = 0; tile < 10; tile++){
        __syncthreads();
        const float4* src = (tile < 9) ? (const float4*)(g3 + tile*4096) : (const float4*)rt3;
        float4* dst = (float4*)gt;
        #pragma unroll
        for (int r = 0; r < 4; r++) dst[t + 256*r] = src[t + 256*r];
        __syncthreads();
        if (tile < 9){
            #pragma unroll 8
            for (int ii = 0; ii < 64; ii++) acc += gt[ii*64 + l] * wbuf[w][tile*64 + ii];
        } else {
            #pragma unroll 8
            for (int ii = 0; ii < 64; ii++) racc += gt[ii*64 + l] * xns[w][ii];
        }
    }
    float inv = 1.f / (float)max(deg, 1);
    float h = eluf(acc*inv + racc + b3[l]);
    if (active) atomicAdd(&gpart[(size_t)(n & 63)*64 + l], h);
}

__global__ void final_kernel(const float* __restrict__ gpart, const float* __restrict__ fw,
                             const float* __restrict__ fb, float* __restrict__ out, int C2){
    __shared__ float gs[64];
    __shared__ float red[2*64];
    int t = threadIdx.x;           // 128 threads
    int o = t & 63, h = t >> 6;
    float a = 0.f;
    for (int p = h*32; p < h*32 + 32; p++) a += gpart[p*64 + o];
    red[h*64 + o] = a;
    __syncthreads();
    if (t < 64) gs[t] = (red[t] + red[64+t]) / (float)C2;
    __syncthreads();
    float acc = fb[t];
    for (int o2 = 0; o2 < 64; o2++) acc += gs[o2] * fw[o2*128 + t];
    out[t] = acc;
}

extern "C" void kernel_launch(void* const* d_in, const int* in_sizes, int n_in,
                              void* d_out, int out_size, void* d_ws, size_t ws_size,
                              hipStream_t stream)
{
    const float* x    = (const float*)d_in[0];
    const float* pos  = (const float*)d_in[1];
    const int*   ei1  = (const int*)d_in[2];
    const int*   cl1  = (const int*)d_in[3];
    const int*   ei2  = (const int*)d_in[4];
    const int*   cl2  = (const int*)d_in[5];
    const int*   ei3  = (const int*)d_in[6];
    const float* g1   = (const float*)d_in[8];
    const float* mu1  = (const float*)d_in[9];
    const float* sg1  = (const float*)d_in[10];
    const float* rt1  = (const float*)d_in[11];
    const float* b1   = (const float*)d_in[12];
    const float* g2   = (const float*)d_in[13];
    const float* mu2  = (const float*)d_in[14];
    const float* sg2  = (const float*)d_in[15];
    const float* rt2  = (const float*)d_in[16];
    const float* b2   = (const float*)d_in[17];
    const float* g3   = (const float*)d_in[18];
    const float* mu3  = (const float*)d_in[19];
    const float* sg3  = (const float*)d_in[20];
    const float* rt3  = (const float*)d_in[21];
    const float* b3   = (const float*)d_in[22];
    const float* fw   = (const float*)d_in[23];
    const float* fb   = (const float*)d_in[24];
    float* out = (float*)d_out;

    const int N  = in_sizes[0];
    const int E1 = in_sizes[2] / 2;
    const int C1 = in_sizes[5];
    const int E2 = in_sizes[4] / 2;
    const int C2 = in_sizes[7];
    const int E3 = in_sizes[6] / 2;

    // workspace layout (float4 arrays first for 16B alignment; counts are multiples of 4)
    float* w = (float*)d_ws;
    size_t off = 0;
    float4* xp1    = (float4*)(w + off); off += (size_t)4*N;
    float4* pos2s4 = (float4*)(w + off); off += (size_t)4*C1;   // zero-region start
    float4* pos3s4 = (float4*)(w + off); off += (size_t)4*C2;
    float*  gpart  = w + off;            off += 64*64;
    int* rp1 = (int*)(w + off); off += (size_t)N + 1;
    int* rp2 = (int*)(w + off); off += (size_t)C1 + 1;
    int* rp3 = (int*)(w + off); off += (size_t)C2 + 1;
    unsigned* h2m = (unsigned*)(w + off); off += (size_t)C1 * 32;  // max-region (contiguous)
    unsigned* h3m = (unsigned*)(w + off); off += (size_t)C2 * 64;

    const int nmax = C1*32 + C2*64;
    const int nz   = 4*C1 + 4*C2 + 64*64;
    prep_kernel<<<dim3(1024), dim3(256), 0, stream>>>(x, pos, N,
        ei1, E1, ei2, E2, C1, ei3, E3, C2,
        rp1, rp2, rp3, h2m, nmax, (float*)pos2s4, nz, xp1);

    l1_kernel<<<dim3((N + 15)/16), dim3(256), 0, stream>>>(xp1, ei1, E1, rp1, cl1,
        g1, mu1, sg1, rt1, b1, h2m, pos2s4, N);
    l2_kernel<<<dim3((C1 + 3)/4), dim3(256), 0, stream>>>(h2m, pos2s4, ei2, E2, rp2, cl2,
        g2, mu2, sg2, rt2, b2, h3m, pos3s4, C1);
    l3_kernel<<<dim3((C2 + 3)/4), dim3(256), 0, stream>>>(h3m, pos3s4, ei3, E3, rp3,
        g3, mu3, sg3, rt3, b3, gpart, C2);
    final_kernel<<<dim3(1), dim3(128), 0, stream>>>(gpart, fw, fb, out, C2);
}